// Round 6
// baseline (63.274 us; speedup 1.0000x reference)
//
#include <hip/hip_runtime.h>

typedef unsigned short u16;
typedef unsigned int   u32;
typedef __attribute__((ext_vector_type(8))) short short8;
typedef __attribute__((ext_vector_type(4))) float f32x4;

__device__ __forceinline__ u16 f2bf(float f) {
    u32 u = __float_as_uint(f);
    u = (u + 0x7fffu + ((u >> 16) & 1u)) >> 16;
    return (u16)u;
}

__device__ __forceinline__ void gld_lds16(const void* g, void* l) {
    __builtin_amdgcn_global_load_lds(
        (const __attribute__((address_space(1))) u32*)g,
        (__attribute__((address_space(3))) u32*)l, 16, 0, 0);
}

// A-matrices stored fragment-major: A'[r>>4][k>>3][r&15][k&7]  dims [64][128][16][8]
__device__ __forceinline__ int ridx(int r, int k) {
    return ((((r >> 4) << 7) + (k >> 3)) << 7) + ((r & 15) << 3) + (k & 7);
}

// ---------------------------------------------------------------------------
// prep: 5122 blocks. A-matrices (cast + transposes) written RETILED;
// Xt and Wt stay linear.
// ---------------------------------------------------------------------------
__global__ __launch_bounds__(256) void prep_kernel(
    const float* __restrict__ x, const float* __restrict__ adj,
    const float* __restrict__ wct, const float* __restrict__ W,
    u16* __restrict__ Ab, u16* __restrict__ W0T, u16* __restrict__ W1T,
    u16* __restrict__ Xt, u16* __restrict__ Wt)
{
    __shared__ float tile[64][65];
    const int t = threadIdx.x;
    const int bid = blockIdx.x;

    if (bid < 3072) {
        const int i4 = bid * 256 + t;
        const float4 v = (i4 < 262144) ? ((const float4*)adj)[i4]
                                       : ((const float4*)wct)[i4 - 262144];
        ushort4 o;
        o.x = f2bf(v.x); o.y = f2bf(v.y); o.z = f2bf(v.z); o.w = f2bf(v.w);
        const int m  = i4 >> 18;
        const int lf = i4 & 262143;
        const int r  = lf >> 8;
        const int k  = (lf & 255) << 2;
        *(ushort4*)&Ab[m * 1048576 + ridx(r, k)] = o;
        return;
    }

    const float* src; u16* dst; int C, R, r0, c0, retile;
    if (bid < 3328)      { const int q = bid - 3072; src = wct;           dst = W0T; C = 1024; R = 1024; r0 = (q & 15) << 6; c0 = (q >> 4) << 6; retile = 1; }
    else if (bid < 3584) { const int q = bid - 3328; src = wct + 1048576; dst = W1T; C = 1024; R = 1024; r0 = (q & 15) << 6; c0 = (q >> 4) << 6; retile = 1; }
    else if (bid < 5120) { const int q = bid - 3584; src = x;             dst = Xt;  C = 2048; R = 3072; r0 = (q % 48) << 6; c0 = (q / 48) << 6; retile = 0; }
    else                 { const int q = bid - 5120; src = W;             dst = Wt;  C = 128;  R = 64;   r0 = 0;             c0 = q << 6;        retile = 0; }

#pragma unroll
    for (int it = 0; it < 4; ++it) {
        const int f4 = it * 256 + t;
        const int r  = f4 >> 4;
        const int c4 = (f4 & 15) << 2;
        const float4 v = *(const float4*)&src[(size_t)(r0 + r) * C + c0 + c4];
        tile[r][c4]     = v.x; tile[r][c4 + 1] = v.y;
        tile[r][c4 + 2] = v.z; tile[r][c4 + 3] = v.w;
    }
    __syncthreads();
#pragma unroll
    for (int it = 0; it < 4; ++it) {
        const int f4 = it * 256 + t;
        const int u  = f4 >> 4;
        const int v4 = (f4 & 15) << 2;
        ushort4 o;
        o.x = f2bf(tile[v4][u]);     o.y = f2bf(tile[v4 + 1][u]);
        o.z = f2bf(tile[v4 + 2][u]); o.w = f2bf(tile[v4 + 3][u]);
        if (retile) *(ushort4*)&dst[ridx(c0 + u, r0 + v4)] = o;
        else        *(ushort4*)&dst[(size_t)(c0 + u) * R + r0 + v4] = o;
    }
}

// ---------------------------------------------------------------------------
// gemm+glu fused. Block tile 128Mx64N, BK=64, 4 waves as 4Mx1N (wave 32x64).
// A: direct L2->VGPR from retiled layout, prefetched 1 step (counted vmcnt).
// B: LDS double-buffer (2x8KB), slot-XOR swizzled, gld_lds staged.
// 768 blocks = 3/CU, one block of each i-round per CU (balanced).
// ---------------------------------------------------------------------------
__global__ __launch_bounds__(256, 3) void gemm_h_kernel(
    const u16* __restrict__ Ab,  const u16* __restrict__ W0b,
    const u16* __restrict__ W1b, const u16* __restrict__ W0T,
    const u16* __restrict__ W1T, const u16* __restrict__ Xt,
    const u16* __restrict__ Wt,  const float* __restrict__ bias,
    float* __restrict__ out)
{
    __shared__ u16 Bdb[8192];     // 2 x 4096 elems; epilogue: Hsm [n128][cin64]
    __shared__ u16 Wsm[8192];     // [c 128][cin 64], slot-swizzled
    __shared__ float Bias_sm[128];

    const int tid = threadIdx.x;
    const int bid = blockIdx.x;
    const int xcd = bid & 7;
    const int idx = bid >> 3;              // 0..95 per XCD
    const int i   = idx >> 5;              // block-row 0..2 (= dispatch round)
    const int idp = idx & 31;
    const int nt   = (xcd << 2) + (idp & 3);   // 0..31 (one b each)
    const int row0 = (idp >> 2) << 7;          // 0..7 x 128

    const int l    = tid & 63;
    const int w    = tid >> 6;
    const int lrow = l & 15;
    const int g16  = l >> 4;

    // ---- stage Wsm (pre-swizzled src) + bias
    {
        u16* wdst = Wsm + (w << 9);
#pragma unroll
        for (int p = 0; p < 4; ++p) {
            const int flat = p * 256 + tid;
            const int row = flat >> 3, slot = flat & 7;
            gld_lds16(Wt + row * 64 + ((slot ^ (row & 7)) << 3), wdst + p * 2048);
        }
        if (tid < 128) Bias_sm[tid] = bias[tid];
    }

    // ---- B staging: thread covers rows {tid>>3, tid>>3+32}, slot tid&7
    const int brow = tid >> 3;
    const int srck = ((tid & 7) ^ (brow & 7)) << 3;
    auto stageB = [&](u16* buf, const u16* tb, int k0) {
        const u16* g0 = tb + (size_t)brow * 3072 + k0 + srck;
        gld_lds16(g0,             buf + (w << 9));
        gld_lds16(g0 + 32 * 3072, buf + (w << 9) + 2048);
    };

    // ---- A direct loads (retiled): wave w owns rows [row0+w*32, +32)
    const int rbw = w << 1;
    auto loadA4 = [&](short8* d, const u16* ta, int k0) {
        const u16* base = ta + (((rbw << 7) + (k0 >> 3)) << 7) + (l << 3);
        d[0] = *(const short8*)(base);                   // fm0 kk0
        d[1] = *(const short8*)(base + 512);             // fm0 kk1
        d[2] = *(const short8*)(base + 16384);           // fm1 kk0
        d[3] = *(const short8*)(base + 16384 + 512);     // fm1 kk1
    };

    f32x4 acc[2][4] = {};
    short8 aC[4], aN[4];

    const size_t xbase = (size_t)nt * 64 * 3072;
    const u16 *ca, *cb, *na, *nb, *fa = nullptr, *fb = nullptr;
    int nterms;
    if (i == 0) {
        ca = Ab  + (row0 << 10); cb = Xt + xbase;
        na = W0b + (row0 << 10); nb = Xt + xbase + 1024;
        nterms = 2;
    } else if (i == 1) {
        ca = W0T + (row0 << 10); cb = Xt + xbase;
        na = Ab  + (row0 << 10); nb = Xt + xbase + 1024;
        fa = W1b + (row0 << 10); fb = Xt + xbase + 2048;
        nterms = 3;
    } else {
        ca = W1T + (row0 << 10); cb = Xt + xbase + 1024;
        na = Ab  + (row0 << 10); nb = Xt + xbase + 2048;
        nterms = 2;
    }

    stageB(Bdb, cb, 0);
    loadA4(aC, ca, 0);

    for (int t = 0; t < nterms; ++t) {
#pragma unroll
        for (int k = 0; k < 16; ++k) {
            u16* bufc = Bdb + ((k & 1) << 12);
            u16* bufp = Bdb + (((k + 1) & 1) << 12);
            const u16* pa = (k < 15) ? ca : na;
            const u16* pb = (k < 15) ? cb : nb;
            const int pk0 = (k < 15) ? ((k + 1) << 6) : 0;
            const bool pf = (k < 15) || (na != nullptr);

            __builtin_amdgcn_s_barrier();               // all done reading bufp
            if (pf) {
                stageB(bufp, pb, pk0);
                loadA4(aN, pa, pk0);
                asm volatile("s_waitcnt vmcnt(10)" ::: "memory");  // B(k) landed
            } else {
                asm volatile("s_waitcnt vmcnt(4)" ::: "memory");
            }
            __builtin_amdgcn_s_barrier();               // bufc globally ready

            short8 bfr[2][4];
#pragma unroll
            for (int kk = 0; kk < 2; ++kk) {
                const int kidx = (kk << 2) | g16;
#pragma unroll
                for (int fn = 0; fn < 4; ++fn) {
                    const int col = (fn << 4) + lrow;
                    bfr[kk][fn] = *(const short8*)&bufc[(col << 6) + ((kidx ^ (col & 7)) << 3)];
                }
            }
#pragma unroll
            for (int kk = 0; kk < 2; ++kk)
#pragma unroll
                for (int fm = 0; fm < 2; ++fm)
#pragma unroll
                    for (int fn = 0; fn < 4; ++fn)
                        acc[fm][fn] = __builtin_amdgcn_mfma_f32_16x16x32_bf16(
                            aC[(fm << 1) | kk], bfr[kk][fn], acc[fm][fn], 0, 0, 0);
#pragma unroll
            for (int j = 0; j < 4; ++j) aC[j] = aN[j];
        }
        ca = na; cb = nb; na = fa; nb = fb; fa = nullptr; fb = nullptr;
    }

    // ---- epilogue: Hsm <- bf16(acc) (into B dbuf, swizzled), then GLU(H@W+b)
    __syncthreads();
    u16* Hsm = Bdb;   // [n 128][cin 64]
#pragma unroll
    for (int fm = 0; fm < 2; ++fm)
#pragma unroll
        for (int fn = 0; fn < 4; ++fn)
#pragma unroll
            for (int r = 0; r < 4; ++r) {
                const int n   = (w << 5) + (fm << 4) + (g16 << 2) + r;
                const int cin = (fn << 4) + lrow;
                Hsm[(n << 6) + (((cin >> 3) ^ (n & 7)) << 3) + (cin & 7)] = f2bf(acc[fm][fn][r]);
            }

    // second GEMM: wave w computes out rows n = w*32..+31, all 128 W-cols
    f32x4 acc2[2][8];
#pragma unroll
    for (int fm2 = 0; fm2 < 2; ++fm2)
#pragma unroll
        for (int fn = 0; fn < 8; ++fn) {
            const float bv = Bias_sm[(fn << 4) + lrow];
            acc2[fm2][fn] = (f32x4){bv, bv, bv, bv};
        }
#pragma unroll
    for (int kk = 0; kk < 2; ++kk) {
        const int gg = (kk << 2) | g16;
        short8 ah[2], bw[8];
#pragma unroll
        for (int fm2 = 0; fm2 < 2; ++fm2) {
            const int n = (w << 5) + (fm2 << 4) + lrow;
            ah[fm2] = *(const short8*)&Hsm[(n << 6) + ((gg ^ (n & 7)) << 3)];
        }
#pragma unroll
        for (int fn = 0; fn < 8; ++fn) {
            const int c = (fn << 4) + lrow;
            bw[fn] = *(const short8*)&Wsm[(c << 6) + ((gg ^ (c & 7)) << 3)];
        }
#pragma unroll
        for (int fm2 = 0; fm2 < 2; ++fm2)
#pragma unroll
            for (int fn = 0; fn < 8; ++fn)
                acc2[fm2][fn] = __builtin_amdgcn_mfma_f32_16x16x32_bf16(
                    ah[fm2], bw[fn], acc2[fm2][fn], 0, 0, 0);
    }

    const int n0g = (i << 10) + row0;
#pragma unroll
    for (int fm2 = 0; fm2 < 2; ++fm2)
#pragma unroll
        for (int fn = 0; fn < 4; ++fn)
#pragma unroll
            for (int r = 0; r < 4; ++r) {
                const int nl = (w << 5) + (fm2 << 4) + (g16 << 2) + r;
                const float lhs = acc2[fm2][fn][r];
                const float rhs = acc2[fm2][fn + 4][r];
                const float sg  = 1.0f / (1.0f + __expf(-rhs));
                const int c = (fn << 4) + lrow;
                out[((size_t)(n0g + nl) * 32 + nt) * 64 + c] = lhs * sg;
            }
}

// ---------------------------------------------------------------------------
extern "C" void kernel_launch(void* const* d_in, const int* in_sizes, int n_in,
                              void* d_out, int out_size, void* d_ws, size_t ws_size,
                              hipStream_t stream)
{
    const float* x    = (const float*)d_in[0];   // (3072, 32, 64)
    const float* adj  = (const float*)d_in[1];   // (1024, 1024)
    const float* wct  = (const float*)d_in[2];   // (2, 1024, 1024)
    const float* W    = (const float*)d_in[3];   // (64, 128)
    const float* bias = (const float*)d_in[4];   // (128,)
    float* out = (float*)d_out;

    char* ws = (char*)d_ws;
    u16* Xt  = (u16*)ws;                    // bf16 [2048][3072] linear
    u16* Ab  = (u16*)(ws + 12582912);       // 3 x 1M bf16, RETILED (Ab|W0b|W1b)
    u16* W0b = Ab + 1048576;
    u16* W1b = Ab + 2097152;
    u16* W0T = (u16*)(ws + 18874368);       // 2 x 1M bf16, RETILED
    u16* W1T = W0T + 1048576;
    u16* Wt  = (u16*)(ws + 23068672);       // bf16 [128][64] linear

    prep_kernel<<<5122, 256, 0, stream>>>(x, adj, wct, W, Ab, W0T, W1T, Xt, Wt);
    gemm_h_kernel<<<768, 256, 0, stream>>>(Ab, W0b, W1b, W0T, W1T, Xt, Wt, bias, out);
}